// Round 1
// 909.015 us; speedup vs baseline: 1.0364x; 1.0364x over previous
//
#include <hip/hip_runtime.h>
#include <math.h>

#define DM 64      // d_manifold
#define RF 64      // n_rff
#define STRENGTH 0.1f
#define SQRT_2_OVER_R 0.17677669529663687f   // sqrt(2/64)
#define NBATCH 8   // fixed by setup_inputs (flat sizes cannot separate B from T)

typedef float vf4 __attribute__((ext_vector_type(4)));

__device__ __forceinline__ float wave_reduce_sum(float v) {
    #pragma unroll
    for (int off = 32; off > 0; off >>= 1)
        v += __shfl_xor(v, off, 64);
    return v;
}

// Pass 1: per-token mass & phi. Stores phi to workspace (8 MiB) and
// accumulates phi_sum[b][r] = sum_t phi*mass.
// One wave per 16 tokens; lane index doubles as hidden index i and RFF index r.
// All loop-invariant weights live in registers (constant-indexed after unroll).
__global__ __launch_bounds__(256) void gravity_pass1(
        const float* __restrict__ coords,   // [B,T,D]
        const float* __restrict__ w1,       // [D,D]
        const float* __restrict__ b1,       // [D]
        const float* __restrict__ w2,       // [D] (shape (1,D))
        const float* __restrict__ b2,       // [1]
        const float* __restrict__ Wr,       // [D,R]
        const float* __restrict__ br,       // [R]
        float* __restrict__ phi_out,        // [B*T, R]
        float* __restrict__ phi_sum,        // [B,R] (pre-zeroed)
        int T) {
    const int lane = threadIdx.x & 63;
    const int wave = threadIdx.x >> 6;      // 0..3
    const int b    = blockIdx.y;
    const int wavesPerBatch = gridDim.x * 4;
    const int waveIdx = blockIdx.x * 4 + wave;

    // --- invariant preloads: w1 row (lane=i) and W column (lane=r) -> VGPRs ---
    float w1r[DM];
    #pragma unroll
    for (int q = 0; q < DM / 4; ++q) {
        vf4 t = *reinterpret_cast<const vf4*>(w1 + (size_t)lane * DM + q * 4);
        w1r[q * 4 + 0] = t[0];
        w1r[q * 4 + 1] = t[1];
        w1r[q * 4 + 2] = t[2];
        w1r[q * 4 + 3] = t[3];
    }
    float wc[DM];
    #pragma unroll
    for (int k = 0; k < DM; ++k) wc[k] = Wr[k * RF + lane];
    const float b1l = b1[lane];
    const float brl = br[lane];
    const float w2l = w2[lane];
    const float b2s = b2[0];

    float acc = 0.f;   // lane r's partial of phi_sum[b][r]

    for (int t = waveIdx; t < T; t += wavesPerBatch) {
        const size_t tok = (size_t)b * T + t;
        float c = coords[tok * DM + lane];
        float h  = b1l;    // lane i: hidden pre-activation
        float pd = brl;    // lane r: RFF phase
        #pragma unroll
        for (int k = 0; k < DM; ++k) {
            float ck = __shfl(c, k, 64);   // constant lane -> readlane
            h  = fmaf(ck, w1r[k], h);
            pd = fmaf(ck, wc[k], pd);
        }
        h = fmaxf(h, 0.f);
        float m = wave_reduce_sum(h * w2l) + b2s;
        // stable softplus = max(x,0) + log1p(exp(-|x|))
        m = fmaxf(m, 0.f) + log1pf(expf(-fabsf(m)));
        float phi = SQRT_2_OVER_R * cosf(pd);
        phi_out[tok * RF + lane] = phi;
        acc = fmaf(phi, m, acc);
    }

    __shared__ float s[4][RF];
    s[wave][lane] = acc;
    __syncthreads();
    if (wave == 0) {
        float v = s[0][lane] + s[1][lane] + s[2][lane] + s[3][lane];
        atomicAdd(&phi_sum[b * RF + lane], v);
    }
}

// Pass 3 (fused former pass 2): each block owns 4 consecutive tokens.
// Prologue: wave w computes grav(token=4*blk+w) = S * dot(phi[tok], phi_sum[b])
// from cached 8 MiB phi. Body: nontemporal stream of G -> out with diagonal add.
__global__ __launch_bounds__(256) void gravity_pass3(
        const float* __restrict__ G,
        const float* __restrict__ phi,      // [B*T, R]
        const float* __restrict__ phi_sum,  // [B, R]
        float* __restrict__ out,
        int T) {
    const int tid  = threadIdx.x;
    const int lane = tid & 63;
    const int w    = tid >> 6;              // 0..3
    const int token = blockIdx.x * 4 + w;
    const int b = token / T;

    __shared__ float gsh[4];
    float v = phi[(size_t)token * RF + lane] * phi_sum[b * RF + lane];
    v = wave_reduce_sum(v);
    if (lane == 0) gsh[w] = STRENGTH * v;
    __syncthreads();

    const vf4* __restrict__ G4   = reinterpret_cast<const vf4*>(G);
    vf4* __restrict__       out4 = reinterpret_cast<vf4*>(out);
    const size_t base = (size_t)blockIdx.x * 4096;   // 4 tokens * 1024 float4

    #pragma unroll
    for (int j = 0; j < 16; ++j) {
        const int il = j * 256 + tid;        // 0..4095 within block's region
        vf4 vv = __builtin_nontemporal_load(&G4[base + il]);
        // token-local index is compile-time: tl = j>>2 (tid<256 never crosses 1024)
        const float g = gsh[j >> 2];
        const int within = (j & 3) * 256 + tid;   // 0..1023 within token
        const int i  = within >> 4;               // row 0..63
        const int j0 = (within & 15) << 2;        // first col of this float4
        const int d  = i - j0;
        if ((unsigned)d < 4u) {
            if      (d == 0) vv[0] += g;
            else if (d == 1) vv[1] += g;
            else if (d == 2) vv[2] += g;
            else             vv[3] += g;
        }
        __builtin_nontemporal_store(vv, &out4[base + il]);
    }
}

extern "C" void kernel_launch(void* const* d_in, const int* in_sizes, int n_in,
                              void* d_out, int out_size, void* d_ws, size_t ws_size,
                              hipStream_t stream) {
    const float* G      = (const float*)d_in[0];
    const float* coords = (const float*)d_in[1];
    const float* w1     = (const float*)d_in[2];
    const float* b1     = (const float*)d_in[3];
    const float* w2     = (const float*)d_in[4];
    const float* b2     = (const float*)d_in[5];
    const float* Wr     = (const float*)d_in[6];
    const float* br     = (const float*)d_in[7];
    float* out          = (float*)d_out;

    const int BT = in_sizes[1] / DM;        // B*T
    const int B  = NBATCH;
    const int T  = BT / B;

    float* phi_sum = (float*)d_ws;                    // B*R floats = 2 KiB
    float* phi     = (float*)d_ws + B * RF;           // B*T*R floats = 8 MiB

    hipMemsetAsync(d_ws, 0, (size_t)B * RF * sizeof(float), stream);

    // Pass 1: 64 blocks/batch x 8 batches, 4 waves/block -> 16 tokens/wave
    dim3 g1(64, B);
    gravity_pass1<<<g1, 256, 0, stream>>>(coords, w1, b1, w2, b2, Wr, br,
                                          phi, phi_sum, T);

    // Pass 3: one block per 4 tokens; grav dot fused in prologue
    gravity_pass3<<<BT / 4, 256, 0, stream>>>(G, phi, phi_sum, out, T);
}

// Round 2
// 902.598 us; speedup vs baseline: 1.0438x; 1.0071x over previous
//
#include <hip/hip_runtime.h>
#include <math.h>

#define DM 64      // d_manifold
#define RF 64      // n_rff
#define STRENGTH 0.1f
#define SQRT_2_OVER_R 0.17677669529663687f   // sqrt(2/64)
#define NBATCH 8   // fixed by setup_inputs (flat sizes cannot separate B from T)

typedef float vf4 __attribute__((ext_vector_type(4)));

__device__ __forceinline__ float wave_reduce_sum(float v) {
    #pragma unroll
    for (int off = 32; off > 0; off >>= 1)
        v += __shfl_xor(v, off, 64);
    return v;   // butterfly: full sum present in ALL lanes
}

// Pass 1: per-token mass & phi. Stores phi to workspace (8 MiB) and
// accumulates phi_sum[b][r] = sum_t phi*mass.
// One wave per 16 tokens; lane index doubles as hidden index i and RFF index r.
// All loop-invariant weights live in registers (constant-indexed after unroll).
__global__ __launch_bounds__(256) void gravity_pass1(
        const float* __restrict__ coords,   // [B,T,D]
        const float* __restrict__ w1,       // [D,D]
        const float* __restrict__ b1,       // [D]
        const float* __restrict__ w2,       // [D] (shape (1,D))
        const float* __restrict__ b2,       // [1]
        const float* __restrict__ Wr,       // [D,R]
        const float* __restrict__ br,       // [R]
        float* __restrict__ phi_out,        // [B*T, R]
        float* __restrict__ phi_sum,        // [B,R] (pre-zeroed)
        int T) {
    const int lane = threadIdx.x & 63;
    const int wave = threadIdx.x >> 6;      // 0..3
    const int b    = blockIdx.y;
    const int wavesPerBatch = gridDim.x * 4;
    const int waveIdx = blockIdx.x * 4 + wave;

    // --- invariant preloads: w1 row (lane=i) and W column (lane=r) -> VGPRs ---
    float w1r[DM];
    #pragma unroll
    for (int q = 0; q < DM / 4; ++q) {
        vf4 t = *reinterpret_cast<const vf4*>(w1 + (size_t)lane * DM + q * 4);
        w1r[q * 4 + 0] = t[0];
        w1r[q * 4 + 1] = t[1];
        w1r[q * 4 + 2] = t[2];
        w1r[q * 4 + 3] = t[3];
    }
    float wc[DM];
    #pragma unroll
    for (int k = 0; k < DM; ++k) wc[k] = Wr[k * RF + lane];
    const float b1l = b1[lane];
    const float brl = br[lane];
    const float w2l = w2[lane];
    const float b2s = b2[0];

    float acc = 0.f;   // lane r's partial of phi_sum[b][r]

    for (int t = waveIdx; t < T; t += wavesPerBatch) {
        const size_t tok = (size_t)b * T + t;
        float c = coords[tok * DM + lane];
        float h  = b1l;    // lane i: hidden pre-activation
        float pd = brl;    // lane r: RFF phase
        #pragma unroll
        for (int k = 0; k < DM; ++k) {
            float ck = __shfl(c, k, 64);   // constant lane -> readlane
            h  = fmaf(ck, w1r[k], h);
            pd = fmaf(ck, wc[k], pd);
        }
        h = fmaxf(h, 0.f);
        float m = wave_reduce_sum(h * w2l) + b2s;
        // stable softplus = max(x,0) + log1p(exp(-|x|))
        m = fmaxf(m, 0.f) + log1pf(expf(-fabsf(m)));
        float phi = SQRT_2_OVER_R * cosf(pd);
        phi_out[tok * RF + lane] = phi;
        acc = fmaf(phi, m, acc);
    }

    __shared__ float s[4][RF];
    s[wave][lane] = acc;
    __syncthreads();
    if (wave == 0) {
        float v = s[0][lane] + s[1][lane] + s[2][lane] + s[3][lane];
        atomicAdd(&phi_sum[b * RF + lane], v);
    }
}

// Pass 3: each WAVE owns one token — no LDS, no __syncthreads.
// Wave computes grav(token) via butterfly reduce (independent of the G
// loads, which are all issued first and cover the reduce latency), then
// does a write burst with the diagonal add folded in.
__global__ __launch_bounds__(256) void gravity_pass3(
        const float* __restrict__ G,
        const float* __restrict__ phi,      // [B*T, R]
        const float* __restrict__ phi_sum,  // [B, R]
        float* __restrict__ out,
        int T) {
    const int tid   = threadIdx.x;
    const int lane  = tid & 63;
    const int w     = tid >> 6;             // 0..3
    const int token = blockIdx.x * 4 + w;
    const int b     = token / T;

    const vf4* __restrict__ G4   = reinterpret_cast<const vf4*>(G);
    vf4* __restrict__       out4 = reinterpret_cast<vf4*>(out);
    const size_t base = (size_t)token * 1024 + lane;   // 1024 float4 per token

    // read burst: 16 KB per wave, independent of grav computation
    vf4 d[16];
    #pragma unroll
    for (int i = 0; i < 16; ++i)
        d[i] = __builtin_nontemporal_load(&G4[base + i * 64]);

    // grav for this wave's token (reduce hides under the loads above)
    float v = phi[(size_t)token * RF + lane] * phi_sum[b * RF + lane];
    const float g = STRENGTH * wave_reduce_sum(v);

    // write burst with diagonal add
    #pragma unroll
    for (int i = 0; i < 16; ++i) {
        const int il  = i * 64 + lane;      // 0..1023 within token
        const int row = il >> 4;            // 0..63
        const int c0  = (il & 15) << 2;     // first col of this float4
        const int dd  = row - c0;
        vf4 vv = d[i];
        if ((unsigned)dd < 4u) {
            if      (dd == 0) vv[0] += g;
            else if (dd == 1) vv[1] += g;
            else if (dd == 2) vv[2] += g;
            else              vv[3] += g;
        }
        __builtin_nontemporal_store(vv, &out4[base + i * 64]);
    }
}

extern "C" void kernel_launch(void* const* d_in, const int* in_sizes, int n_in,
                              void* d_out, int out_size, void* d_ws, size_t ws_size,
                              hipStream_t stream) {
    const float* G      = (const float*)d_in[0];
    const float* coords = (const float*)d_in[1];
    const float* w1     = (const float*)d_in[2];
    const float* b1     = (const float*)d_in[3];
    const float* w2     = (const float*)d_in[4];
    const float* b2     = (const float*)d_in[5];
    const float* Wr     = (const float*)d_in[6];
    const float* br     = (const float*)d_in[7];
    float* out          = (float*)d_out;

    const int BT = in_sizes[1] / DM;        // B*T
    const int B  = NBATCH;
    const int T  = BT / B;

    float* phi_sum = (float*)d_ws;                    // B*R floats = 2 KiB
    float* phi     = (float*)d_ws + B * RF;           // B*T*R floats = 8 MiB

    hipMemsetAsync(d_ws, 0, (size_t)B * RF * sizeof(float), stream);

    // Pass 1: 64 blocks/batch x 8 batches, 4 waves/block -> 16 tokens/wave
    dim3 g1(64, B);
    gravity_pass1<<<g1, 256, 0, stream>>>(coords, w1, b1, w2, b2, Wr, br,
                                          phi, phi_sum, T);

    // Pass 3: one wave per token, no intra-block coupling
    gravity_pass3<<<BT / 4, 256, 0, stream>>>(G, phi, phi_sum, out, T);
}